// Round 5
// baseline (305.154 us; speedup 1.0000x reference)
//
#include <hip/hip_runtime.h>
#include <hip/hip_bf16.h>
#include <math.h>

#define Hd   512
#define FPd  256
#define Ed   512
#define NFd  768
#define Ld   512
#define Bd   32
#define K2H  1024            // 2H
#define Nd   1024            // NF + FP
#define Md   (Ld * Bd)       // 16384

typedef _Float16 f16x8  __attribute__((ext_vector_type(8)));
typedef _Float16 f16x4  __attribute__((ext_vector_type(4)));
typedef float    f32x16 __attribute__((ext_vector_type(16)));

// ---------------------------------------------------------------------------
// Kernel 1: W_big[n][k] (fp32, [1024][1024])
//   n <  NF: sum_e F[n][e]    * W_feat[e][k]
//   n >= NF: sum_h v[n-NF][h] * W_lin[h][k]
// ---------------------------------------------------------------------------
__global__ __launch_bounds__(256)
void build_wbig(const float* __restrict__ F,
                const float* __restrict__ Wf,
                const float* __restrict__ V,
                const float* __restrict__ Wl,
                float* __restrict__ Wbig) {
    __shared__ float fs[32][64];
    const int tid = threadIdx.x;
    const int n0  = blockIdx.y * 32;
    const int k   = blockIdx.x * 128 + (tid & 127);
    const int ty  = tid >> 7;

    const float* src;  const float* wsrc;
    if (n0 < NFd) { src = F + (size_t)n0 * Ed;          wsrc = Wf; }
    else          { src = V + (size_t)(n0 - NFd) * Hd;  wsrc = Wl; }

    float acc[16];
#pragma unroll
    for (int i = 0; i < 16; i++) acc[i] = 0.f;

    for (int e0 = 0; e0 < 512; e0 += 64) {
#pragma unroll
        for (int rep = 0; rep < 2; rep++) {
            int idx = rep * 256 + tid;
            int i   = idx >> 4;
            int kq  = idx & 15;
            float4 v4 = *(const float4*)(src + (size_t)i * 512 + e0 + kq * 4);
            *(float4*)(&fs[i][kq * 4]) = v4;
        }
        __syncthreads();
#pragma unroll 4
        for (int kk = 0; kk < 64; kk += 4) {
            float w0 = wsrc[(size_t)(e0 + kk + 0) * K2H + k];
            float w1 = wsrc[(size_t)(e0 + kk + 1) * K2H + k];
            float w2 = wsrc[(size_t)(e0 + kk + 2) * K2H + k];
            float w3 = wsrc[(size_t)(e0 + kk + 3) * K2H + k];
#pragma unroll
            for (int i = 0; i < 16; i++) {
                float4 f4 = *(const float4*)(&fs[ty * 16 + i][kk]);
                acc[i] += f4.x * w0 + f4.y * w1 + f4.z * w2 + f4.w * w3;
            }
        }
        __syncthreads();
    }
#pragma unroll
    for (int i = 0; i < 16; i++)
        Wbig[(size_t)(n0 + ty * 16 + i) * K2H + k] = acc[i];
}

// ---------------------------------------------------------------------------
// Kernel 1b: bias_big[n]
// ---------------------------------------------------------------------------
__global__ __launch_bounds__(64)
void build_bias(const float* __restrict__ F, const float* __restrict__ bf,
                const float* __restrict__ V, const float* __restrict__ bl,
                float* __restrict__ bias) {
    const int n    = blockIdx.x;
    const int lane = threadIdx.x;
    const float* row; const float* bsrc;
    if (n < NFd) { row = F + (size_t)n * Ed;          bsrc = bf; }
    else         { row = V + (size_t)(n - NFd) * Hd;  bsrc = bl; }
    float a = 0.f;
#pragma unroll
    for (int rep = 0; rep < 8; rep++) {
        int e = rep * 64 + lane;
        a += row[e] * bsrc[e];
    }
#pragma unroll
    for (int off = 1; off < 64; off <<= 1) a += __shfl_xor(a, off);
    if (lane == 0) bias[n] = a;
}

// ---------------------------------------------------------------------------
// Kernel 2: repack Wbig fp32 -> fp16 hi/lo in MFMA B-fragment layout.
// frag index = ((ntile*64 + kk)*64 + lane), each frag = 8 f16 (16B).
// n = ntile*32 + (lane&31), k = kk*16 + (lane>>5)*8 + j.
// ---------------------------------------------------------------------------
__global__ __launch_bounds__(256)
void repack_b(const float* __restrict__ Wbig,
              _Float16* __restrict__ Bhi, _Float16* __restrict__ Blo) {
    const int gid  = blockIdx.x * 256 + threadIdx.x;   // 0..131071
    const int lane = gid & 63;
    const int ks   = (gid >> 6) & 63;
    const int nt   = gid >> 12;
    const int n = nt * 32 + (lane & 31);
    const int k = ks * 16 + (lane >> 5) * 8;
    const float* src = Wbig + (size_t)n * K2H + k;
    f16x8 h, l;
#pragma unroll
    for (int j = 0; j < 8; j++) {
        float a = src[j];
        _Float16 hh = (_Float16)a;
        h[j] = hh;
        l[j] = (_Float16)(a - (float)hh);
    }
    *(f16x8*)(Bhi + (size_t)gid * 8) = h;
    *(f16x8*)(Blo + (size_t)gid * 8) = l;
}

// ---------------------------------------------------------------------------
// Kernel 3: MFMA GEMM (fp16x3 split) + fused softmax + DIRECT transposed
// store to out[b][n][l].
// Grid 512 = (b, lq): block covers rows m = {(lq*32+i)*32 + b, i=0..31},
// i.e. fixed batch b, 32 consecutive l. 512 thr = 8 waves; wave wn owns
// cols wn*128 (4 n-tiles of 32). acc = 4 x f32x16 (64 AGPR).
// A: staged per 64-k chunk into LDS as f16 hi/lo planes (XOR-swizzled),
// converted ONCE per element. 1 barrier per chunk; stage-load issued
// before the barrier (async-stage split). B: direct global frag loads.
// ---------------------------------------------------------------------------
__global__ __launch_bounds__(512, 4)
void gemm_direct(const float* __restrict__ enc,
                 const _Float16* __restrict__ Bh,
                 const _Float16* __restrict__ Bl,
                 const float* __restrict__ bias,
                 float* __restrict__ out) {
    // LDS: 2 bufs x (hi,lo planes) x [32 rows][64 k] f16 = 16 KB
    __shared__ char AsB[16384];
    __shared__ float red[8][32];
    __shared__ float redc[32];

    const int tid  = threadIdx.x;
    const int lane = tid & 63;
    const int wn   = tid >> 6;         // wave 0..7 -> col block
    const int hf   = lane >> 5;
    const int l31  = lane & 31;
    const int b    = blockIdx.x >> 4;  // 0..31
    const int l0   = (blockIdx.x & 15) * 32;

    f32x16 acc[4];
#pragma unroll
    for (int nt = 0; nt < 4; nt++)
#pragma unroll
        for (int r = 0; r < 16; r++) acc[nt][r] = 0.f;

    // staging map: thread -> (row = tid>>4, 4 k at (tid&15)*4)
    const int srow = tid >> 4;
    const int sk4  = (tid & 15) * 4;
    const float* gA = enc + ((size_t)(l0 + srow) * Bd + b) * K2H + sk4;
    const uint32_t wb = (uint32_t)((srow * 128 + sk4 * 2) ^ ((srow & 7) << 4));

    // prologue: stage chunk 0 into buf 0
    {
        float4 p = *(const float4*)gA;
        float av[4] = {p.x, p.y, p.z, p.w};
        f16x4 h, l;
#pragma unroll
        for (int j = 0; j < 4; j++) {
            _Float16 hh = (_Float16)av[j];
            h[j] = hh;
            l[j] = (_Float16)(av[j] - (float)hh);
        }
        *(f16x4*)(AsB + wb)        = h;
        *(f16x4*)(AsB + 4096 + wb) = l;
    }

    const uint32_t ra = (uint32_t)((l31 * 128 + hf * 16) ^ ((l31 & 7) << 4));

    for (int c = 0; c < 16; ++c) {
        float4 p;
        if (c < 15) p = *(const float4*)(gA + (c + 1) * 64);   // issue early
        __syncthreads();   // buf[c&1] ready; buf[(c+1)&1] free
        const char* base = AsB + (c & 1) * 8192;
#pragma unroll
        for (int kkl = 0; kkl < 4; ++kkl) {
            const int kk = c * 4 + kkl;
            f16x8 a_h = *(const f16x8*)(base + (ra ^ (uint32_t)(kkl * 32)));
            f16x8 a_l = *(const f16x8*)(base + 4096 + (ra ^ (uint32_t)(kkl * 32)));
#pragma unroll
            for (int nt = 0; nt < 4; ++nt) {
                const size_t fo = ((size_t)((wn * 4 + nt) * 64 + kk) * 64 + lane) * 8;
                f16x8 b_h = *(const f16x8*)(Bh + fo);
                f16x8 b_l = *(const f16x8*)(Bl + fo);
                acc[nt] = __builtin_amdgcn_mfma_f32_32x32x16_f16(a_h, b_h, acc[nt], 0, 0, 0);
                acc[nt] = __builtin_amdgcn_mfma_f32_32x32x16_f16(a_l, b_h, acc[nt], 0, 0, 0);
                acc[nt] = __builtin_amdgcn_mfma_f32_32x32x16_f16(a_h, b_l, acc[nt], 0, 0, 0);
            }
        }
        if (c < 15) {      // convert + write into buf[(c+1)&1]
            float av[4] = {p.x, p.y, p.z, p.w};
            f16x4 h, l;
#pragma unroll
            for (int j = 0; j < 4; j++) {
                _Float16 hh = (_Float16)av[j];
                h[j] = hh;
                l[j] = (_Float16)(av[j] - (float)hh);
            }
            char* wbase = AsB + ((c + 1) & 1) * 8192;
            *(f16x4*)(wbase + wb)        = h;
            *(f16x4*)(wbase + 4096 + wb) = l;
        }
    }

    // ---- epilogue: bias + softmax over N + direct transposed store ----
    // C/D layout: col n = lane&31, row rr = (r&3) + 8*(r>>2) + 4*hf
    float bv[4];
#pragma unroll
    for (int nt = 0; nt < 4; nt++) bv[nt] = bias[wn * 128 + nt * 32 + l31];
#pragma unroll
    for (int nt = 0; nt < 4; nt++)
#pragma unroll
        for (int r = 0; r < 16; r++) acc[nt][r] += bv[nt];

    // per-row max (across 4 nt, then across the 32 lanes of this hf group)
#pragma unroll
    for (int r = 0; r < 16; r++) {
        float mx = fmaxf(fmaxf(acc[0][r], acc[1][r]), fmaxf(acc[2][r], acc[3][r]));
#pragma unroll
        for (int off = 1; off < 32; off <<= 1) mx = fmaxf(mx, __shfl_xor(mx, off));
        if (l31 == r) red[wn][(r & 3) + 8 * (r >> 2) + 4 * hf] = mx;
    }
    __syncthreads();
    if (tid < 32) {
        float v = red[0][tid];
#pragma unroll
        for (int w = 1; w < 8; w++) v = fmaxf(v, red[w][tid]);
        redc[tid] = v;
    }
    __syncthreads();

    // exp + partial sums
#pragma unroll
    for (int r = 0; r < 16; r++) {
        const int rr = (r & 3) + 8 * (r >> 2) + 4 * hf;
        const float rm = redc[rr];
        float s = 0.f;
#pragma unroll
        for (int nt = 0; nt < 4; nt++) {
            float e = __expf(acc[nt][r] - rm);
            acc[nt][r] = e;
            s += e;
        }
#pragma unroll
        for (int off = 1; off < 32; off <<= 1) s += __shfl_xor(s, off);
        if (l31 == r) red[wn][rr] = s;
    }
    __syncthreads();
    if (tid < 32) {
        float v = 0.f;
#pragma unroll
        for (int w = 0; w < 8; w++) v += red[w][tid];
        redc[tid] = 1.0f / v;
    }
    __syncthreads();

    float invr[16];
#pragma unroll
    for (int r = 0; r < 16; r++) invr[r] = redc[(r & 3) + 8 * (r >> 2) + 4 * hf];

    // store: out[b][n][l0 + rr], rr = (r&3)+8*(r>>2)+4*hf -> float4 per g
#pragma unroll
    for (int nt = 0; nt < 4; nt++) {
        const int n = wn * 128 + nt * 32 + l31;
        float* op = out + ((size_t)b * Nd + n) * Ld + l0 + hf * 4;
#pragma unroll
        for (int g = 0; g < 4; g++) {
            float4 v = make_float4(acc[nt][g * 4 + 0] * invr[g * 4 + 0],
                                   acc[nt][g * 4 + 1] * invr[g * 4 + 1],
                                   acc[nt][g * 4 + 2] * invr[g * 4 + 2],
                                   acc[nt][g * 4 + 3] * invr[g * 4 + 3]);
            *(float4*)(op + 8 * g) = v;
        }
    }
}

// ---------------------------------------------------------------------------
// Workspace layout (8.2 MB):
//   Wbig f32 [1024][1024]  4 MB @ 0x0
//   bias f32 [1024]        4 KB @ 0x400000
//   Bh   f16 [1M]          2 MB @ 0x410000
//   Bl   f16 [1M]          2 MB @ 0x610000
// ---------------------------------------------------------------------------
extern "C" void kernel_launch(void* const* d_in, const int* in_sizes, int n_in,
                              void* d_out, int out_size, void* d_ws, size_t ws_size,
                              hipStream_t stream) {
    (void)in_sizes; (void)n_in; (void)out_size; (void)ws_size;

    const float* F    = (const float*)d_in[0];   // (768, 512)
    const float* enc  = (const float*)d_in[1];   // (512, 32, 1024)
    const float* Wlin = (const float*)d_in[2];   // (512, 1024)
    const float* blin = (const float*)d_in[3];   // (512,)
    const float* Wfea = (const float*)d_in[4];   // (512, 1024)
    const float* bfea = (const float*)d_in[5];   // (512,)
    const float* V    = (const float*)d_in[6];   // (256, 512)
    float* out = (float*)d_out;                  // (32, 1024, 512)

    char* ws = (char*)d_ws;
    float*    Wbig = (float*)ws;                  // 4 MB
    float*    bias = (float*)(ws + 0x400000);     // 4 KB
    _Float16* Bh   = (_Float16*)(ws + 0x410000);  // 2 MB
    _Float16* Bl   = (_Float16*)(ws + 0x610000);  // 2 MB

    build_wbig<<<dim3(8, 32), 256, 0, stream>>>(F, Wfea, V, Wlin, Wbig);
    build_bias<<<dim3(1024), 64, 0, stream>>>(F, bfea, V, blin, bias);
    repack_b<<<dim3(512), 256, 0, stream>>>(Wbig, Bh, Bl);
    gemm_direct<<<dim3(512), 512, 0, stream>>>(enc, Bh, Bl, bias, out);
}

// Round 7
// 287.789 us; speedup vs baseline: 1.0603x; 1.0603x over previous
//
#include <hip/hip_runtime.h>
#include <hip/hip_bf16.h>
#include <math.h>

#define Hd   512
#define FPd  256
#define Ed   512
#define NFd  768
#define Ld   512
#define Bd   32
#define K2H  1024            // 2H
#define Nd   1024            // NF + FP
#define Md   (Ld * Bd)       // 16384

typedef _Float16 f16x8  __attribute__((ext_vector_type(8)));
typedef float    f32x16 __attribute__((ext_vector_type(16)));

// ---------------------------------------------------------------------------
// Kernel 1: W_big[n][k] (fp32, [1024][1024])
//   n <  NF: sum_e F[n][e]    * W_feat[e][k]
//   n >= NF: sum_h v[n-NF][h] * W_lin[h][k]
// ---------------------------------------------------------------------------
__global__ __launch_bounds__(256)
void build_wbig(const float* __restrict__ F,
                const float* __restrict__ Wf,
                const float* __restrict__ V,
                const float* __restrict__ Wl,
                float* __restrict__ Wbig) {
    __shared__ float fs[32][64];
    const int tid = threadIdx.x;
    const int n0  = blockIdx.y * 32;
    const int k   = blockIdx.x * 128 + (tid & 127);
    const int ty  = tid >> 7;

    const float* src;  const float* wsrc;
    if (n0 < NFd) { src = F + (size_t)n0 * Ed;          wsrc = Wf; }
    else          { src = V + (size_t)(n0 - NFd) * Hd;  wsrc = Wl; }

    float acc[16];
#pragma unroll
    for (int i = 0; i < 16; i++) acc[i] = 0.f;

    for (int e0 = 0; e0 < 512; e0 += 64) {
#pragma unroll
        for (int rep = 0; rep < 2; rep++) {
            int idx = rep * 256 + tid;
            int i   = idx >> 4;
            int kq  = idx & 15;
            float4 v4 = *(const float4*)(src + (size_t)i * 512 + e0 + kq * 4);
            *(float4*)(&fs[i][kq * 4]) = v4;
        }
        __syncthreads();
#pragma unroll 4
        for (int kk = 0; kk < 64; kk += 4) {
            float w0 = wsrc[(size_t)(e0 + kk + 0) * K2H + k];
            float w1 = wsrc[(size_t)(e0 + kk + 1) * K2H + k];
            float w2 = wsrc[(size_t)(e0 + kk + 2) * K2H + k];
            float w3 = wsrc[(size_t)(e0 + kk + 3) * K2H + k];
#pragma unroll
            for (int i = 0; i < 16; i++) {
                float4 f4 = *(const float4*)(&fs[ty * 16 + i][kk]);
                acc[i] += f4.x * w0 + f4.y * w1 + f4.z * w2 + f4.w * w3;
            }
        }
        __syncthreads();
    }
#pragma unroll
    for (int i = 0; i < 16; i++)
        Wbig[(size_t)(n0 + ty * 16 + i) * K2H + k] = acc[i];
}

// ---------------------------------------------------------------------------
// Kernel 1b: bias_big[n]
// ---------------------------------------------------------------------------
__global__ __launch_bounds__(64)
void build_bias(const float* __restrict__ F, const float* __restrict__ bf,
                const float* __restrict__ V, const float* __restrict__ bl,
                float* __restrict__ bias) {
    const int n    = blockIdx.x;
    const int lane = threadIdx.x;
    const float* row; const float* bsrc;
    if (n < NFd) { row = F + (size_t)n * Ed;          bsrc = bf; }
    else         { row = V + (size_t)(n - NFd) * Hd;  bsrc = bl; }
    float a = 0.f;
#pragma unroll
    for (int rep = 0; rep < 8; rep++) {
        int e = rep * 64 + lane;
        a += row[e] * bsrc[e];
    }
#pragma unroll
    for (int off = 1; off < 64; off <<= 1) a += __shfl_xor(a, off);
    if (lane == 0) bias[n] = a;
}

// ---------------------------------------------------------------------------
// Kernel 2: repack Wbig fp32 -> fp16 hi/lo in MFMA B-fragment layout.
// frag index = ((ntile*64 + kk)*64 + lane), each frag = 8 f16 (16B).
// n = ntile*32 + (lane&31), k = kk*16 + (lane>>5)*8 + j.
// ---------------------------------------------------------------------------
__global__ __launch_bounds__(256)
void repack_b(const float* __restrict__ Wbig,
              _Float16* __restrict__ Bhi, _Float16* __restrict__ Blo) {
    const int gid  = blockIdx.x * 256 + threadIdx.x;   // 0..131071
    const int lane = gid & 63;
    const int ks   = (gid >> 6) & 63;
    const int nt   = gid >> 12;
    const int n = nt * 32 + (lane & 31);
    const int k = ks * 16 + (lane >> 5) * 8;
    const float* src = Wbig + (size_t)n * K2H + k;
    f16x8 h, l;
#pragma unroll
    for (int j = 0; j < 8; j++) {
        float a = src[j];
        _Float16 hh = (_Float16)a;
        h[j] = hh;
        l[j] = (_Float16)(a - (float)hh);
    }
    *(f16x8*)(Bhi + (size_t)gid * 8) = h;
    *(f16x8*)(Blo + (size_t)gid * 8) = l;
}

// ---------------------------------------------------------------------------
// Kernel 3: MFMA GEMM (fp16x3 split) + fused softmax + direct transposed
// store to out[b][n][l].
// Grid 256 = (b, lc): block = fixed batch b, 64 consecutive l (64 m-rows).
// 512 thr = 8 waves; wave wn owns cols wn*128 (4 nt of 32) x 64 rows
// (2 ms of 32) -> acc[2][4] f32x16 = 128 AGPR; each B-frag feeds 2 MFMAs.
// A: BK=128 chunks staged to LDS as f16 hi/lo planes (converted ONCE),
// double-buffered, XOR-swizzled; prefetch issued right after the barrier
// so it flies under the 192-MFMA phase. B: direct global frag loads
// (L2/L3-resident, 1 GB total). Bias pre-folded into acc init.
// ---------------------------------------------------------------------------
__global__ __launch_bounds__(512, 2)
void gemm_direct(const float* __restrict__ enc,
                 const _Float16* __restrict__ Bh,
                 const _Float16* __restrict__ Bl,
                 const float* __restrict__ bias,
                 float* __restrict__ out) {
    // 2 bufs x (hi plane 16KB | lo plane 16KB) : rows 0..63, 128 k f16 each
    __shared__ char AsB[2][32768];
    __shared__ float red[8][64];
    __shared__ float redc[64];

    const int tid  = threadIdx.x;
    const int lane = tid & 63;
    const int wn   = tid >> 6;         // wave 0..7 -> col block
    const int hf   = lane >> 5;
    const int l31  = lane & 31;
    const int b    = blockIdx.x >> 3;  // 0..31
    const int l0   = (blockIdx.x & 7) * 64;

    // bias folded into accumulator init (C/D col = l31 -> same per row)
    float bv[4];
#pragma unroll
    for (int nt = 0; nt < 4; nt++) bv[nt] = bias[wn * 128 + nt * 32 + l31];
    f32x16 acc[2][4];
#pragma unroll
    for (int ms = 0; ms < 2; ms++)
#pragma unroll
        for (int nt = 0; nt < 4; nt++)
#pragma unroll
            for (int r = 0; r < 16; r++) acc[ms][nt][r] = bv[nt];

    // staging map: thread -> (row = tid>>3 in 0..63, 16 k at (tid&7)*16)
    const int srow = tid >> 3;
    const int skf  = (tid & 7) * 16;                   // k float offset
    const float* gA = enc + ((size_t)(l0 + srow) * Bd + b) * K2H + skf;
    const uint32_t wswz = (uint32_t)((srow & 15) << 4);
    const uint32_t wb0  = (uint32_t)(srow * 256 + skf * 2);   // byte offset

    // read map: row = ms*32 + l31 -> row&15 == l31&15
    const uint32_t rswz = (uint32_t)((l31 & 15) << 4);

    // prologue: stage chunk 0 into buf 0
    {
        float pf[16];
#pragma unroll
        for (int j = 0; j < 4; j++)
            *(float4*)(pf + 4 * j) = *(const float4*)(gA + 4 * j);
        f16x8 h0, h1, lo0, lo1;
#pragma unroll
        for (int j = 0; j < 8; j++) {
            _Float16 a = (_Float16)pf[j];     h0[j] = a;  lo0[j] = (_Float16)(pf[j] - (float)a);
            _Float16 c = (_Float16)pf[8 + j]; h1[j] = c;  lo1[j] = (_Float16)(pf[8 + j] - (float)c);
        }
        char* base = AsB[0];
        *(f16x8*)(base + ((wb0)      ^ wswz)) = h0;
        *(f16x8*)(base + ((wb0 + 16) ^ wswz)) = h1;
        *(f16x8*)(base + 16384 + ((wb0)      ^ wswz)) = lo0;
        *(f16x8*)(base + 16384 + ((wb0 + 16) ^ wswz)) = lo1;
    }

    for (int c = 0; c < 8; ++c) {
        __syncthreads();               // buf[c&1] staged; buf[(c+1)&1] free
        float pf[16];
        if (c < 7) {                   // issue prefetch NOW: flies under MFMA
            const float* g = gA + (c + 1) * 128;
#pragma unroll
            for (int j = 0; j < 4; j++)
                *(float4*)(pf + 4 * j) = *(const float4*)(g + 4 * j);
        }
        const char* hbase = AsB[c & 1];
        const char* lbase = AsB[c & 1] + 16384;
#pragma unroll
        for (int kk = 0; kk < 8; ++kk) {
            const uint32_t ko = (uint32_t)((kk * 32 + hf * 16) ^ rswz);
            f16x8 a_h[2], a_l[2];
#pragma unroll
            for (int ms = 0; ms < 2; ms++) {
                const uint32_t ro = (uint32_t)((ms * 32 + l31) * 256);
                a_h[ms] = *(const f16x8*)(hbase + ro + ko);
                a_l[ms] = *(const f16x8*)(lbase + ro + ko);
            }
#pragma unroll
            for (int nt = 0; nt < 4; ++nt) {
                const size_t fo = ((size_t)((wn * 4 + nt) * 64 + c * 8 + kk) * 64 + lane) * 8;
                f16x8 b_h = *(const f16x8*)(Bh + fo);
                f16x8 b_l = *(const f16x8*)(Bl + fo);
                acc[0][nt] = __builtin_amdgcn_mfma_f32_32x32x16_f16(a_h[0], b_h, acc[0][nt], 0, 0, 0);
                acc[1][nt] = __builtin_amdgcn_mfma_f32_32x32x16_f16(a_h[1], b_h, acc[1][nt], 0, 0, 0);
                acc[0][nt] = __builtin_amdgcn_mfma_f32_32x32x16_f16(a_l[0], b_h, acc[0][nt], 0, 0, 0);
                acc[1][nt] = __builtin_amdgcn_mfma_f32_32x32x16_f16(a_l[1], b_h, acc[1][nt], 0, 0, 0);
                acc[0][nt] = __builtin_amdgcn_mfma_f32_32x32x16_f16(a_h[0], b_l, acc[0][nt], 0, 0, 0);
                acc[1][nt] = __builtin_amdgcn_mfma_f32_32x32x16_f16(a_h[1], b_l, acc[1][nt], 0, 0, 0);
            }
        }
        if (c < 7) {                   // convert once + write next buffer
            f16x8 h0, h1, lo0, lo1;
#pragma unroll
            for (int j = 0; j < 8; j++) {
                _Float16 a = (_Float16)pf[j];     h0[j] = a;  lo0[j] = (_Float16)(pf[j] - (float)a);
                _Float16 d = (_Float16)pf[8 + j]; h1[j] = d;  lo1[j] = (_Float16)(pf[8 + j] - (float)d);
            }
            char* base = AsB[(c + 1) & 1];
            *(f16x8*)(base + ((wb0)      ^ wswz)) = h0;
            *(f16x8*)(base + ((wb0 + 16) ^ wswz)) = h1;
            *(f16x8*)(base + 16384 + ((wb0)      ^ wswz)) = lo0;
            *(f16x8*)(base + 16384 + ((wb0 + 16) ^ wswz)) = lo1;
        }
    }

    // ---- epilogue: softmax over N (bias already in acc) + direct store ----
    // C/D layout: col n = lane&31, row rr = (r&3) + 8*(r>>2) + 4*hf
#pragma unroll
    for (int ms = 0; ms < 2; ms++) {
#pragma unroll
        for (int r = 0; r < 16; r++) {
            float mx = fmaxf(fmaxf(acc[ms][0][r], acc[ms][1][r]),
                             fmaxf(acc[ms][2][r], acc[ms][3][r]));
#pragma unroll
            for (int off = 1; off < 32; off <<= 1) mx = fmaxf(mx, __shfl_xor(mx, off));
            if (l31 == r) red[wn][ms * 32 + (r & 3) + 8 * (r >> 2) + 4 * hf] = mx;
        }
    }
    __syncthreads();
    if (tid < 64) {
        float v = red[0][tid];
#pragma unroll
        for (int w = 1; w < 8; w++) v = fmaxf(v, red[w][tid]);
        redc[tid] = v;
    }
    __syncthreads();

#pragma unroll
    for (int ms = 0; ms < 2; ms++) {
#pragma unroll
        for (int r = 0; r < 16; r++) {
            const int rr = ms * 32 + (r & 3) + 8 * (r >> 2) + 4 * hf;
            const float rm = redc[rr];
            float s = 0.f;
#pragma unroll
            for (int nt = 0; nt < 4; nt++) {
                float e = __expf(acc[ms][nt][r] - rm);
                acc[ms][nt][r] = e;
                s += e;
            }
#pragma unroll
            for (int off = 1; off < 32; off <<= 1) s += __shfl_xor(s, off);
            if (l31 == r) red[wn][rr] = s;
        }
    }
    __syncthreads();
    if (tid < 64) {
        float v = 0.f;
#pragma unroll
        for (int w = 0; w < 8; w++) v += red[w][tid];
        redc[tid] = 1.0f / v;
    }
    __syncthreads();

#pragma unroll
    for (int ms = 0; ms < 2; ms++) {
        float invr[16];
#pragma unroll
        for (int r = 0; r < 16; r++)
            invr[r] = redc[ms * 32 + (r & 3) + 8 * (r >> 2) + 4 * hf];
#pragma unroll
        for (int nt = 0; nt < 4; nt++) {
            const int n = wn * 128 + nt * 32 + l31;
            float* op = out + ((size_t)b * Nd + n) * Ld + l0 + ms * 32 + hf * 4;
#pragma unroll
            for (int g = 0; g < 4; g++) {
                float4 v = make_float4(acc[ms][nt][g * 4 + 0] * invr[g * 4 + 0],
                                       acc[ms][nt][g * 4 + 1] * invr[g * 4 + 1],
                                       acc[ms][nt][g * 4 + 2] * invr[g * 4 + 2],
                                       acc[ms][nt][g * 4 + 3] * invr[g * 4 + 3]);
                *(float4*)(op + 8 * g) = v;
            }
        }
    }
}

// ---------------------------------------------------------------------------
// Workspace layout (8.2 MB):
//   Wbig f32 [1024][1024]  4 MB @ 0x0
//   bias f32 [1024]        4 KB @ 0x400000
//   Bh   f16 [1M]          2 MB @ 0x410000
//   Bl   f16 [1M]          2 MB @ 0x610000
// ---------------------------------------------------------------------------
extern "C" void kernel_launch(void* const* d_in, const int* in_sizes, int n_in,
                              void* d_out, int out_size, void* d_ws, size_t ws_size,
                              hipStream_t stream) {
    (void)in_sizes; (void)n_in; (void)out_size; (void)ws_size;

    const float* F    = (const float*)d_in[0];   // (768, 512)
    const float* enc  = (const float*)d_in[1];   // (512, 32, 1024)
    const float* Wlin = (const float*)d_in[2];   // (512, 1024)
    const float* blin = (const float*)d_in[3];   // (512,)
    const float* Wfea = (const float*)d_in[4];   // (512, 1024)
    const float* bfea = (const float*)d_in[5];   // (512,)
    const float* V    = (const float*)d_in[6];   // (256, 512)
    float* out = (float*)d_out;                  // (32, 1024, 512)

    char* ws = (char*)d_ws;
    float*    Wbig = (float*)ws;                  // 4 MB
    float*    bias = (float*)(ws + 0x400000);     // 4 KB
    _Float16* Bh   = (_Float16*)(ws + 0x410000);  // 2 MB
    _Float16* Bl   = (_Float16*)(ws + 0x610000);  // 2 MB

    build_wbig<<<dim3(8, 32), 256, 0, stream>>>(F, Wfea, V, Wlin, Wbig);
    build_bias<<<dim3(1024), 64, 0, stream>>>(F, bfea, V, blin, bias);
    repack_b<<<dim3(512), 256, 0, stream>>>(Wbig, Bh, Bl);
    gemm_direct<<<dim3(256), 512, 0, stream>>>(enc, Bh, Bl, bias, out);
}